// Round 3
// baseline (337.094 us; speedup 1.0000x reference)
//
#include <hip/hip_runtime.h>
#include <hip/hip_bf16.h>
#include <stdint.h>

#define B_ 4
#define S_ 4096
#define E_ 1024
#define H_ 16
#define D_ 64
#define M_ (B_*S_)          // 16384 rows
constexpr float kEPS = 1e-6f;

typedef unsigned short u16;
typedef unsigned char  u8;
typedef __bf16 bf16x8 __attribute__((ext_vector_type(8)));
typedef float  f32x4  __attribute__((ext_vector_type(4)));
typedef u16    u16x8  __attribute__((ext_vector_type(8)));

typedef const __attribute__((address_space(1))) void* gaddr_t;
typedef __attribute__((address_space(3))) void*       laddr_t;

__device__ __forceinline__ u16 f2bf(float f) {
    union { float f; uint32_t u; } v; v.f = f;
    uint32_t u = v.u;
    u += 0x7fffu + ((u >> 16) & 1u);   // RNE
    return (u16)(u >> 16);
}
__device__ __forceinline__ float bf2f(u16 h) {
    union { uint32_t u; float f; } v; v.u = ((uint32_t)h) << 16;
    return v.f;
}
__device__ __forceinline__ float hi2f(uint32_t d) {   // high 16 bits as bf16
    union { uint32_t u; float f; } v; v.u = d & 0xffff0000u;
    return v.f;
}
__device__ __forceinline__ float lo2f(uint32_t d) {   // low 16 bits as bf16
    union { uint32_t u; float f; } v; v.u = d << 16;
    return v.f;
}

#define VM_WAIT(n) asm volatile("s_waitcnt vmcnt(" #n ")" ::: "memory")
#define LG0        asm volatile("s_waitcnt lgkmcnt(0)" ::: "memory")
#define BAR        do { __builtin_amdgcn_s_barrier(); __builtin_amdgcn_sched_barrier(0); } while (0)

// ---------------- f32 -> bf16 conversion (weights only now) ----------------
__global__ void cvt_kernel(const float* __restrict__ in, u16* __restrict__ out, int n4) {
    int i = blockIdx.x * blockDim.x + threadIdx.x;
    if (i >= n4) return;
    float4 v = reinterpret_cast<const float4*>(in)[i];
    ushort4 o;
    o.x = f2bf(v.x); o.y = f2bf(v.y); o.z = f2bf(v.z); o.w = f2bf(v.w);
    reinterpret_cast<ushort4*>(out)[i] = o;
}

#define BM 256
#define BN 256
#define BK 32
#define NT (E_/BK)          // 32 K-tiles
#define TILE (BM*BK)        // 8192 u16 = 16 KB

// ============ GEMM with fused f32->bf16 A-staging (QKV projections) ============
// C = A_f32 @ W_bf16^T (+bias, epilogue). 3 LDS buffers, counted vmcnt(6).
// EPI: 1 = relu(x+b)+eps -> bf16; 2 = EPI1 + mask-zero; 3 = x+b -> bf16
struct AReg { f32x4 r[4]; };

template<int EPI>
__global__ __launch_bounds__(512, 2)
void gemm_f32a(const float* __restrict__ Af, const u16* __restrict__ Bw,
               const float* __restrict__ bias, const u8* __restrict__ mask,
               u16* __restrict__ Cb)
{
    extern __shared__ u16 lds[];          // 3*TILE A + 3*TILE B = 96 KB
    u16* Asb = lds;
    u16* Bsb = lds + 3*TILE;

    const int tid  = threadIdx.x;
    const int wid  = tid >> 6, lane = tid & 63;
    const int wr   = wid >> 2, wc = wid & 3;      // 2 x 4 waves
    const int m0   = blockIdx.x * BM;             // x = m-tile: the 4 n-blocks sharing A are 64 apart -> same XCD
    const int n0   = blockIdx.y * BN;
    const int fr   = lane & 15;                   // fragment row
    const int cg   = lane >> 4;                   // k-chunk group 0..3

    // ---- A staging geometry (reg-staged f32): thread -> (row, half of 32-k window) ----
    const int arow  = tid >> 1;          // 0..255
    const int ahalf = tid & 1;           // 16 f32 each
    const int afrow = (arow >> 1) & 3;   // LDS chunk swizzle key
    const int aslot0 = (ahalf*2)     ^ afrow;
    const int aslot1 = (ahalf*2 + 1) ^ afrow;
    const float* aBase = Af + (size_t)(m0 + arow)*E_ + ahalf*16;

    // ---- B staging geometry (gload_lds, pre-swizzled source) ----
    const int sb0 = tid, sb1 = tid + 512;
    const int brow0 = sb0 >> 2, bc0 = (sb0 & 3) ^ ((brow0 >> 1) & 3);
    const int brow1 = sb1 >> 2, bc1 = (sb1 & 3) ^ ((brow1 >> 1) & 3);
    const u16* b0p = Bw + (size_t)(n0 + brow0)*E_ + bc0*8;
    const u16* b1p = Bw + (size_t)(n0 + brow1)*E_ + bc1*8;

    // ---- fragment read offsets (u16 elements), swizzled ----
    const int fsw = (fr >> 1) & 3;
    int aoff[8], boff[4];
#pragma unroll
    for (int mf = 0; mf < 8; ++mf)
        aoff[mf] = (wr*128 + mf*16 + fr)*BK + ((cg ^ fsw) * 8);
#pragma unroll
    for (int nf = 0; nf < 4; ++nf)
        boff[nf] = (wc*64 + nf*16 + fr)*BK + ((cg ^ fsw) * 8);

    f32x4 acc[8][4] = {};

    float bias_v[4];
#pragma unroll
    for (int nf = 0; nf < 4; ++nf) bias_v[nf] = bias[n0 + wc*64 + nf*16 + fr];

    AReg RA, RB;

    auto issueA = [&](AReg& R, int t) {
        const float* p = aBase + (size_t)t*BK;
#pragma unroll
        for (int i = 0; i < 4; ++i) R.r[i] = *reinterpret_cast<const f32x4*>(p + i*4);
    };
    auto cvtw = [&](const AReg& R, int buf) {
        bf16x8 h0, h1;
#pragma unroll
        for (int j = 0; j < 4; ++j) {
            h0[j]   = (__bf16)R.r[0][j];
            h0[4+j] = (__bf16)R.r[1][j];
            h1[j]   = (__bf16)R.r[2][j];
            h1[4+j] = (__bf16)R.r[3][j];
        }
        u16* base = Asb + buf*TILE + arow*BK;
        *reinterpret_cast<bf16x8*>(base + aslot0*8) = h0;
        *reinterpret_cast<bf16x8*>(base + aslot1*8) = h1;
    };
    auto stgB = [&](int t, int buf) {
        const size_t ke = (size_t)t * BK;
        __builtin_amdgcn_global_load_lds((gaddr_t)(b0p + ke), (laddr_t)(Bsb + buf*TILE + sb0*8), 16, 0, 0);
        __builtin_amdgcn_global_load_lds((gaddr_t)(b1p + ke), (laddr_t)(Bsb + buf*TILE + sb1*8), 16, 0, 0);
    };
    auto compute = [&](int cb) {
        const u16* Ab = Asb + cb*TILE;
        const u16* Bb = Bsb + cb*TILE;
        bf16x8 af[8], bfv[4];
#pragma unroll
        for (int nf = 0; nf < 4; ++nf) bfv[nf] = *reinterpret_cast<const bf16x8*>(Bb + boff[nf]);
#pragma unroll
        for (int mf = 0; mf < 8; ++mf) af[mf]  = *reinterpret_cast<const bf16x8*>(Ab + aoff[mf]);
        asm volatile("s_waitcnt lgkmcnt(0)" ::: "memory");
        __builtin_amdgcn_sched_barrier(0);
        __builtin_amdgcn_s_setprio(1);
#pragma unroll
        for (int mf = 0; mf < 8; ++mf)
#pragma unroll
            for (int nf = 0; nf < 4; ++nf)
                acc[mf][nf] = __builtin_amdgcn_mfma_f32_16x16x32_bf16(af[mf], bfv[nf], acc[mf][nf], 0, 0, 0);
        __builtin_amdgcn_s_setprio(0);
    };

    // prologue: A0->RA, A1->RB, write A0, B0/B1 staged
    issueA(RA, 0);
    issueA(RB, 1);
    VM_WAIT(4);              // A0 done (A1 in flight)
    cvtw(RA, 0);
    stgB(0, 0);
    stgB(1, 1);
    LG0; BAR;
    // queue: [A1(4), B0(2), B1(2)] = 8

#define GBODY(T, XREG, YREG) do { \
        issueA(XREG, (T)+2); \
        VM_WAIT(6); \
        cvtw(YREG, ((T)+1)%3); \
        LG0; BAR; \
        stgB((T)+2, ((T)+2)%3); \
        compute((T)%3); \
    } while (0)

#pragma unroll 1
    for (int tp = 0; tp < 15; ++tp) {
        const int t = tp*2;
        GBODY(t,   RA, RB);
        GBODY(t+1, RB, RA);
    }
    // t = 30: queue [B30, A31, B31]
    VM_WAIT(2);
    cvtw(RB, 1);             // A31 -> buf 31%3 = 1
    LG0; BAR;
    compute(0);              // tile 30
    // t = 31
    VM_WAIT(0);
    BAR;
    compute(1);              // tile 31
#undef GBODY

    // ---- epilogue ----
#pragma unroll
    for (int mf = 0; mf < 8; ++mf) {
#pragma unroll
        for (int nf = 0; nf < 4; ++nf) {
            const int gn = n0 + wc*64 + nf*16 + fr;
#pragma unroll
            for (int r = 0; r < 4; ++r) {
                const int gm = m0 + wr*128 + mf*16 + cg*4 + r;
                float x = acc[mf][nf][r] + bias_v[nf];
                if (EPI == 1) {
                    x = fmaxf(x, 0.f) + kEPS;
                    Cb[(size_t)gm*E_ + gn] = f2bf(x);
                } else if (EPI == 2) {
                    x = fmaxf(x, 0.f) + kEPS;
                    if (mask[gm]) x = 0.f;
                    Cb[(size_t)gm*E_ + gn] = f2bf(x);
                } else {
                    Cb[(size_t)gm*E_ + gn] = f2bf(x);
                }
            }
        }
    }
}

// ============ bf16-A GEMM (output projection), EPI0: f32 out + bias ============
template<int EPI>
__global__ __launch_bounds__(512, 2)
void gemm_bt(const u16* __restrict__ A, const u16* __restrict__ Bw,
             const float* __restrict__ bias, const u8* __restrict__ mask,
             float* __restrict__ Cf, u16* __restrict__ Cb)
{
    extern __shared__ u16 lds[];
    u16* Asb = lds;
    u16* Bsb = lds + 3*TILE;

    const int tid  = threadIdx.x;
    const int wid  = tid >> 6, lane = tid & 63;
    const int wr   = wid >> 2, wc = wid & 3;
    const int m0   = blockIdx.x * BM;
    const int n0   = blockIdx.y * BN;
    const int fr   = lane & 15;
    const int cg   = lane >> 4;

    const int s0 = tid, s1 = tid + 512;
    const int row0 = s0 >> 2, c0 = s0 & 3;
    const int row1 = s1 >> 2, c1 = s1 & 3;
    const int cc0 = c0 ^ ((row0 >> 1) & 3);
    const int cc1 = c1 ^ ((row1 >> 1) & 3);
    const u16* a0p = A  + (size_t)(m0 + row0)*E_ + cc0*8;
    const u16* a1p = A  + (size_t)(m0 + row1)*E_ + cc1*8;
    const u16* b0p = Bw + (size_t)(n0 + row0)*E_ + cc0*8;
    const u16* b1p = Bw + (size_t)(n0 + row1)*E_ + cc1*8;

    const int fsw = (fr >> 1) & 3;
    int aoff[8], boff[4];
#pragma unroll
    for (int mf = 0; mf < 8; ++mf)
        aoff[mf] = (wr*128 + mf*16 + fr)*BK + ((cg ^ fsw) * 8);
#pragma unroll
    for (int nf = 0; nf < 4; ++nf)
        boff[nf] = (wc*64 + nf*16 + fr)*BK + ((cg ^ fsw) * 8);

    f32x4 acc[8][4] = {};

    float bias_v[4];
#pragma unroll
    for (int nf = 0; nf < 4; ++nf) bias_v[nf] = bias[n0 + wc*64 + nf*16 + fr];

    auto STG = [&](int t, int sb) {
        const size_t ke = (size_t)t * BK;
        __builtin_amdgcn_global_load_lds((gaddr_t)(a0p + ke), (laddr_t)(Asb + sb*TILE + s0*8), 16, 0, 0);
        __builtin_amdgcn_global_load_lds((gaddr_t)(a1p + ke), (laddr_t)(Asb + sb*TILE + s1*8), 16, 0, 0);
        __builtin_amdgcn_global_load_lds((gaddr_t)(b0p + ke), (laddr_t)(Bsb + sb*TILE + s0*8), 16, 0, 0);
        __builtin_amdgcn_global_load_lds((gaddr_t)(b1p + ke), (laddr_t)(Bsb + sb*TILE + s1*8), 16, 0, 0);
    };

    auto COMPUTE = [&](int cb) {
        const u16* Ab = Asb + cb*TILE;
        const u16* Bb = Bsb + cb*TILE;
        bf16x8 af[8], bfv[4];
#pragma unroll
        for (int nf = 0; nf < 4; ++nf) bfv[nf] = *reinterpret_cast<const bf16x8*>(Bb + boff[nf]);
#pragma unroll
        for (int mf = 0; mf < 8; ++mf) af[mf]  = *reinterpret_cast<const bf16x8*>(Ab + aoff[mf]);
        asm volatile("s_waitcnt lgkmcnt(0)" ::: "memory");
        __builtin_amdgcn_sched_barrier(0);
        __builtin_amdgcn_s_setprio(1);
#pragma unroll
        for (int mf = 0; mf < 8; ++mf)
#pragma unroll
            for (int nf = 0; nf < 4; ++nf)
                acc[mf][nf] = __builtin_amdgcn_mfma_f32_16x16x32_bf16(af[mf], bfv[nf], acc[mf][nf], 0, 0, 0);
        __builtin_amdgcn_s_setprio(0);
    };

#define W4 do { asm volatile("s_waitcnt vmcnt(4)" ::: "memory"); \
                __builtin_amdgcn_s_barrier(); \
                __builtin_amdgcn_sched_barrier(0); } while (0)
#define W0 do { asm volatile("s_waitcnt vmcnt(0)" ::: "memory"); \
                __builtin_amdgcn_s_barrier(); \
                __builtin_amdgcn_sched_barrier(0); } while (0)

    STG(0, 0);
    STG(1, 1);

#pragma unroll 1
    for (int tb = 0; tb < (NT - 2) / 3; ++tb) {
        const int t = tb * 3;
        W4; STG(t + 2, 2); COMPUTE(0);
        W4; STG(t + 3, 0); COMPUTE(1);
        W4; STG(t + 4, 1); COMPUTE(2);
    }
    W4; COMPUTE(0);
    W0; COMPUTE(1);
#undef W4
#undef W0

#pragma unroll
    for (int mf = 0; mf < 8; ++mf) {
#pragma unroll
        for (int nf = 0; nf < 4; ++nf) {
            const int gn = n0 + wc*64 + nf*16 + fr;
#pragma unroll
            for (int r = 0; r < 4; ++r) {
                const int gm = m0 + wr*128 + mf*16 + cg*4 + r;
                float x = acc[mf][nf][r] + bias_v[nf];
                if (EPI == 0) {
                    Cf[(size_t)gm*E_ + gn] = x;
                } else {
                    Cb[(size_t)gm*E_ + gn] = f2bf(x);
                }
            }
        }
    }
}

// ---------------- stage 2: kv partial = K_chunk^T @ V_chunk ----------------
#define KVS 256             // s-rows per chunk
#define KVCH (S_/KVS)       // 16 chunks
#define KPAD 72             // padded row stride (u16), 144B: conflict-free + 16B-aligned
__global__ __launch_bounds__(256)
void kv_partial_kernel(const u16* __restrict__ Ka, const u16* __restrict__ Vv,
                       float* __restrict__ kvp, float* __restrict__ ksp)
{
    __shared__ u16 Ks[KVS*KPAD];   // 36 KB
    __shared__ u16 Vs[KVS*KPAD];   // 36 KB
    const int bh = blockIdx.x, b = bh >> 4, h = bh & 15;
    const int s0 = blockIdx.y * KVS;
    const int tid = threadIdx.x;

#pragma unroll
    for (int i = 0; i < 8; ++i) {           // 2048 16B-groups
        int g = i*256 + tid;
        int row = g >> 3, c8 = (g & 7) * 8;
        size_t goff = (size_t)(b*S_ + s0 + row)*E_ + h*64 + c8;
        *reinterpret_cast<uint4*>(Ks + row*KPAD + c8) = *reinterpret_cast<const uint4*>(Ka + goff);
        *reinterpret_cast<uint4*>(Vs + row*KPAD + c8) = *reinterpret_cast<const uint4*>(Vv + goff);
    }
    __syncthreads();

    const int dg = tid >> 4;       // d0 = dg*4
    const int vg = tid & 15;       // v0 = vg*4
    float acc[16] = {};
#pragma unroll 4
    for (int s = 0; s < KVS; ++s) {
        uint2 ku = *reinterpret_cast<const uint2*>(Ks + s*KPAD + dg*4);
        uint2 vu = *reinterpret_cast<const uint2*>(Vs + s*KPAD + vg*4);
        float k0 = lo2f(ku.x), k1 = hi2f(ku.x), k2 = lo2f(ku.y), k3 = hi2f(ku.y);
        float v0 = lo2f(vu.x), v1 = hi2f(vu.x), v2 = lo2f(vu.y), v3 = hi2f(vu.y);
        acc[0]  += k0*v0; acc[1]  += k0*v1; acc[2]  += k0*v2; acc[3]  += k0*v3;
        acc[4]  += k1*v0; acc[5]  += k1*v1; acc[6]  += k1*v2; acc[7]  += k1*v3;
        acc[8]  += k2*v0; acc[9]  += k2*v1; acc[10] += k2*v2; acc[11] += k2*v3;
        acc[12] += k3*v0; acc[13] += k3*v1; acc[14] += k3*v2; acc[15] += k3*v3;
    }
    float* dst = kvp + ((size_t)blockIdx.y*64 + bh)*4096;
#pragma unroll
    for (int i = 0; i < 4; ++i) {
        f32x4 o; o[0] = acc[i*4+0]; o[1] = acc[i*4+1]; o[2] = acc[i*4+2]; o[3] = acc[i*4+3];
        *reinterpret_cast<f32x4*>(dst + (dg*4+i)*64 + vg*4) = o;
    }

    // ksum partial: column sums of Ks
    __syncthreads();                    // all Vs reads done -> reuse as scratch
    {
        const int col = tid & 63, grp = tid >> 6;
        float s = 0.f;
#pragma unroll 8
        for (int r = 0; r < 64; ++r) s += bf2f(Ks[(grp*64 + r)*KPAD + col]);
        ((float*)Vs)[grp*64 + col] = s;
    }
    __syncthreads();
    if (tid < 64) {
        const float* sc = (const float*)Vs;
        float t = sc[tid] + sc[64+tid] + sc[128+tid] + sc[192+tid];
        ksp[((size_t)blockIdx.y*64 + bh)*64 + tid] = t;
    }
}

// ---------------- stage 2b: reduce partials -> kvT (bf16) + ksum ----------------
__global__ __launch_bounds__(256)
void kv_reduce_kernel(const float* __restrict__ kvp, const float* __restrict__ ksp,
                      u16* __restrict__ kvT, float* __restrict__ ksum)
{
    __shared__ u16 T[64*KPAD];      // transposed bf16 tile
    const int bh = blockIdx.x, tid = threadIdx.x;
#pragma unroll
    for (int j = 0; j < 16; ++j) {
        int idx = j*256 + tid;
        int d = idx >> 6, v = idx & 63;
        float s = 0.f;
#pragma unroll
        for (int c = 0; c < KVCH; ++c) s += kvp[((size_t)c*64 + bh)*4096 + idx];
        T[v*KPAD + d] = f2bf(s);
    }
    if (tid < 64) {
        float t = 0.f;
#pragma unroll
        for (int c = 0; c < KVCH; ++c) t += ksp[((size_t)c*64 + bh)*64 + tid];
        ksum[bh*64 + tid] = t;
    }
    __syncthreads();
#pragma unroll
    for (int k = 0; k < 2; ++k) {
        int g = k*256 + tid;               // 512 8-u16 groups
        int v = g >> 3, c8 = (g & 7) * 8;
        uint4 q = *reinterpret_cast<const uint4*>(T + v*KPAD + c8);
        *reinterpret_cast<uint4*>(kvT + (size_t)bh*4096 + g*8) = q;
    }
}

// ---------------- stage 3: attn = (Qa @ kv) / max(Qa . ksum, eps), MFMA ----------------
__global__ __launch_bounds__(256)
void attn_kernel(const u16* __restrict__ Qa, const u16* __restrict__ kvT,
                 const float* __restrict__ ksum, u16* __restrict__ attn)
{
    __shared__ u16  Qs[256*64];    // 32 KB, XOR-swizzled storage (8 chunks/row)
    __shared__ u16  Ts[64*64];     // 8 KB, XOR-swizzled
    __shared__ float kss[64];
    __shared__ float invd[256];

    const int bh = blockIdx.x, b = bh >> 4, h = bh & 15;
    const int s0 = blockIdx.y * 256;
    const int tid = threadIdx.x;
    const int wid = tid >> 6, lane = tid & 63;
    const int fr = lane & 15, cg = lane >> 4;

    // Q staging via gload_lds, pre-swizzled global source (rule #21)
#pragma unroll
    for (int j = 0; j < 8; ++j) {
        int L = (wid*8 + j)*64 + lane;      // 16B slot index
        int row = L >> 3, c = L & 7;
        int cs = c ^ (row & 7);
        const u16* src = Qa + (size_t)(b*S_ + s0 + row)*E_ + h*64 + cs*8;
        __builtin_amdgcn_global_load_lds((gaddr_t)src, (laddr_t)(Qs + L*8), 16, 0, 0);
    }
    // kvT staging (reg-staged, swizzled write)
#pragma unroll
    for (int k = 0; k < 2; ++k) {
        int g = k*256 + tid;
        int v = g >> 3, c = g & 7;
        uint4 q = *reinterpret_cast<const uint4*>(kvT + (size_t)bh*4096 + g*8);
        int cs = c ^ (v & 7);
        *reinterpret_cast<uint4*>(Ts + v*64 + cs*8) = q;
    }
    if (tid < 64) kss[tid] = ksum[bh*64 + tid];
    asm volatile("s_waitcnt vmcnt(0) lgkmcnt(0)" ::: "memory");
    __syncthreads();

    // denominator: thread t -> row t
    {
        float den = 0.f;
#pragma unroll
        for (int c = 0; c < 8; ++c) {
            uint4 qc = *reinterpret_cast<const uint4*>(Qs + tid*64 + (c ^ (tid & 7))*8);
            den += lo2f(qc.x)*kss[c*8+0] + hi2f(qc.x)*kss[c*8+1]
                 + lo2f(qc.y)*kss[c*8+2] + hi2f(qc.y)*kss[c*8+3]
                 + lo2f(qc.z)*kss[c*8+4] + hi2f(qc.z)*kss[c*8+5]
                 + lo2f(qc.w)*kss[c*8+6] + hi2f(qc.w)*kss[c*8+7];
        }
        invd[tid] = 1.0f / fmaxf(den, kEPS);
    }
    __syncthreads();

    // MFMA: wave covers rows wid*64..+63, all 64 v
    f32x4 acc[4][4] = {};
#pragma unroll
    for (int ks = 0; ks < 2; ++ks) {
        bf16x8 bfrag[4];
#pragma unroll
        for (int nf = 0; nf < 4; ++nf) {
            int v = nf*16 + fr;
            bfrag[nf] = *reinterpret_cast<const bf16x8*>(Ts + v*64 + ((ks*4 + cg) ^ (v & 7))*8);
        }
#pragma unroll
        for (int mf = 0; mf < 4; ++mf) {
            int m = wid*64 + mf*16 + fr;
            bf16x8 afrag = *reinterpret_cast<const bf16x8*>(Qs + m*64 + ((ks*4 + cg) ^ (m & 7))*8);
#pragma unroll
            for (int nf = 0; nf < 4; ++nf)
                acc[mf][nf] = __builtin_amdgcn_mfma_f32_16x16x32_bf16(afrag, bfrag[nf], acc[mf][nf], 0, 0, 0);
        }
    }

    // epilogue: divide by denom, store bf16
#pragma unroll
    for (int mf = 0; mf < 4; ++mf) {
#pragma unroll
        for (int nf = 0; nf < 4; ++nf) {
            const int v = nf*16 + fr;
#pragma unroll
            for (int r = 0; r < 4; ++r) {
                const int row = wid*64 + mf*16 + cg*4 + r;
                float x = acc[mf][nf][r] * invd[row];
                attn[(size_t)(b*S_ + s0 + row)*E_ + h*64 + v] = f2bf(x);
            }
        }
    }
}

// ---------------- host ----------------
extern "C" void kernel_launch(void* const* d_in, const int* in_sizes, int n_in,
                              void* d_out, int out_size, void* d_ws, size_t ws_size,
                              hipStream_t stream)
{
    const float* query = (const float*)d_in[0];
    const float* key   = (const float*)d_in[1];
    const float* value = (const float*)d_in[2];
    const u8*    mask  = (const u8*)d_in[3];
    const float* Wq = (const float*)d_in[4];
    const float* bq = (const float*)d_in[5];
    const float* Wk = (const float*)d_in[6];
    const float* bk = (const float*)d_in[7];
    const float* Wv = (const float*)d_in[8];
    const float* bv = (const float*)d_in[9];
    const float* Wo = (const float*)d_in[10];
    const float* bo = (const float*)d_in[11];
    float* out = (float*)d_out;

    const size_t SZ_ME = (size_t)M_ * E_;
    const size_t SZ_EE = (size_t)E_ * E_;

    char* ws = (char*)d_ws;
    u16* Qa   = (u16*)ws; ws += SZ_ME*2;
    u16* Ka   = (u16*)ws; ws += SZ_ME*2;
    u16* Vv   = (u16*)ws; ws += SZ_ME*2;
    u16* attnb= (u16*)ws; ws += SZ_ME*2;
    u16* wqb  = (u16*)ws; ws += SZ_EE*2;
    u16* wkb  = (u16*)ws; ws += SZ_EE*2;
    u16* wvb  = (u16*)ws; ws += SZ_EE*2;
    u16* wob  = (u16*)ws; ws += SZ_EE*2;
    float* kvp = (float*)ws; ws += (size_t)KVCH*64*4096*4;   // 16 MiB
    float* ksp = (float*)ws; ws += (size_t)KVCH*64*64*4;     // 256 KiB
    u16*  kvT  = (u16*)ws;  ws += (size_t)64*4096*2;         // 512 KiB
    float* ksum= (float*)ws; ws += 4096*4;

    // 1) weight conversions
    cvt_kernel<<<(int)(SZ_EE/4/256), 256, 0, stream>>>(Wq, wqb, (int)(SZ_EE/4));
    cvt_kernel<<<(int)(SZ_EE/4/256), 256, 0, stream>>>(Wk, wkb, (int)(SZ_EE/4));
    cvt_kernel<<<(int)(SZ_EE/4/256), 256, 0, stream>>>(Wv, wvb, (int)(SZ_EE/4));
    cvt_kernel<<<(int)(SZ_EE/4/256), 256, 0, stream>>>(Wo, wob, (int)(SZ_EE/4));

    // 2) QKV projections with fused f32->bf16 A-staging
    dim3 ggrid(M_/BM, E_/BN);   // (64, 4): the 4 blocks sharing an A-panel are 64 apart -> same XCD
    constexpr size_t LDS_BYTES = 6 * TILE * sizeof(u16);   // 96 KB
    gemm_f32a<1><<<ggrid, 512, LDS_BYTES, stream>>>(query, wqb, bq, nullptr, Qa);
    gemm_f32a<2><<<ggrid, 512, LDS_BYTES, stream>>>(key,   wkb, bk, mask,    Ka);
    gemm_f32a<3><<<ggrid, 512, LDS_BYTES, stream>>>(value, wvb, bv, nullptr, Vv);

    // 3) kv_context + k_sum (two-phase, deterministic)
    kv_partial_kernel<<<dim3(B_*H_, KVCH), 256, 0, stream>>>(Ka, Vv, kvp, ksp);
    kv_reduce_kernel<<<64, 256, 0, stream>>>(kvp, ksp, kvT, ksum);

    // 4) attn numerator / denom (MFMA)
    attn_kernel<<<dim3(B_*H_, S_/256), 256, 0, stream>>>(Qa, kvT, ksum, attnb);

    // 5) output projection -> f32 out
    gemm_bt<0><<<ggrid, 512, LDS_BYTES, stream>>>(attnb, wob, bo, nullptr, out, nullptr);
}